// Round 18
// baseline (564.918 us; speedup 1.0000x reference)
//
#include <hip/hip_runtime.h>
#include <hip/hip_bf16.h>
#include <cmath>

constexpr int NB = 4096;   // batch
constexpr int NH = 1024;   // hidden
constexpr int NE = 8;      // experts
constexpr int NF = 4096;   // dff
constexpr int NG = 512;    // gate hidden (H/2)
constexpr float THRESH = 0.1f;
constexpr int PAD_ROWS = 128;
constexpr size_t MAXS = (size_t)2 * NB;        // <= 8192 routed slots
constexpr size_t ROWS = MAXS + PAD_ROWS;       // padded for tile overreach

// Established (rounds 0-17):
//   ALL inputs f32 C-order positional. d_out f32 [output(B,H) | gate_w(B,E)].
//   ws_size >= ~256 MiB. ~All top-2 pass threshold (S ~ 8175).
//   R11 gload_lds 128x128 GEMM = best structure; dbuf/supertile/8-phase lost.
//   R16/R17: standalone prework stuck at ~155 us, latency-bound (not width).
//   This round: hide tconv under consumers — L1 = gate+tconv(ew1);
//   FFN1 launch += tconv(ew2); FFN2 launch += tconv(pw). k_offsets removed
//   (local prefix from count). GEMM/router/xc/final unchanged from R17.

typedef float  f32x4  __attribute__((ext_vector_type(4)));
typedef __bf16 bf16x8 __attribute__((ext_vector_type(8)));
typedef __bf16 bf16x4 __attribute__((ext_vector_type(4)));

typedef __attribute__((address_space(1))) void gvoid_t;
typedef __attribute__((address_space(3))) void svoid_t;

__device__ __forceinline__ void gl_lds16(const void* g, void* l)
{
    __builtin_amdgcn_global_load_lds((gvoid_t*)g, (svoid_t*)l, 16, 0, 0);
}

__device__ __forceinline__ float silu_f(float v) { return v / (1.f + expf(-v)); }

__global__ void k_sentinel(float* out, float code)
{
    if (threadIdx.x == 0 && blockIdx.x == 0) out[0] = code;
}

// ---------------------------------------------------------------------------
// tconv tile body: 64x64 f32 [R][C] tile -> bf16 [C][R], via LDS stride-65.
// f32x4 global reads, bf16x8 global writes (128B column segments).
// ---------------------------------------------------------------------------
__device__ __forceinline__ void tconv_body(
    const float* __restrict__ I, __bf16* __restrict__ O, int R, int C,
    int bx, int by, float* smem)
{
    const int r0 = by * 64, c0 = bx * 64;
    const int tid = threadIdx.x;
    const int rr = tid >> 4;          // 0..15
    const int c4 = tid & 15;          // 0..15 -> cols c4*4..c4*4+3
#pragma unroll
    for (int i = 0; i < 4; i++) {
        int r = i * 16 + rr;
        f32x4 v = *(const f32x4*)&I[(size_t)(r0 + r) * C + c0 + c4 * 4];
#pragma unroll
        for (int j = 0; j < 4; j++) smem[r * 65 + c4 * 4 + j] = v[j];
    }
    __syncthreads();
    const int cw = tid >> 3;          // 0..31
    const int rp = tid & 7;           // 0..7 -> rows rp*8..rp*8+7
#pragma unroll
    for (int i = 0; i < 2; i++) {
        int c = cw + i * 32;
        bf16x8 v;
#pragma unroll
        for (int j = 0; j < 8; j++)
            v[j] = (__bf16)smem[(rp * 8 + j) * 65 + c];
        *(bf16x8*)&O[(size_t)(c0 + c) * R + r0 + rp * 8] = v;
    }
}

// ---------------------------------------------------------------------------
// L1: gate GEMM (f32 exact) + tconv(ew1), one launch.
//   [0, 512)       gate: hidden = silu(x @ gate_w1 + gate_b1)
//   [512, 8704)    tconv ew1 [e][NH][NF] -> Wt1 [e][NF][NH] bf16
// ---------------------------------------------------------------------------
__global__ __launch_bounds__(256) void k_gate_ew1(
    const float* __restrict__ x, const float* __restrict__ gw1,
    const float* __restrict__ gb1, float* __restrict__ hidden,
    const float* __restrict__ ew1, __bf16* __restrict__ Wt1)
{
    __shared__ float smem[64 * 65];   // 16.6 KB
    int id = blockIdx.x;

    if (id < 512) {
        float* As = smem;              // [16][68]
        float* Bs = smem + 16 * 68;    // [16][64]
        const int tid = threadIdx.x;
        const int r0 = (id >> 3) * 64, c0 = (id & 7) * 64;
        const int tx = tid & 15, ty = tid >> 4;
        float acc[4][4] = {};
        for (int k0 = 0; k0 < NH; k0 += 16) {
#pragma unroll
            for (int i = 0; i < 4; i++) {
                int e = tid + i * 256;
                int m = e >> 4, kk = e & 15;
                As[kk * 68 + m] = x[(size_t)(r0 + m) * NH + k0 + kk];
            }
#pragma unroll
            for (int i = 0; i < 4; i++) {
                int e = tid + i * 256;
                int kk = e >> 6, n = e & 63;
                Bs[kk * 64 + n] = gw1[(size_t)(k0 + kk) * NG + c0 + n];
            }
            __syncthreads();
#pragma unroll
            for (int kk = 0; kk < 16; kk++) {
                f32x4 a = *(const f32x4*)&As[kk * 68 + ty * 4];
                f32x4 b = *(const f32x4*)&Bs[kk * 64 + tx * 4];
#pragma unroll
                for (int i = 0; i < 4; i++)
#pragma unroll
                    for (int j = 0; j < 4; j++)
                        acc[i][j] = fmaf(a[i], b[j], acc[i][j]);
            }
            __syncthreads();
        }
#pragma unroll
        for (int i = 0; i < 4; i++) {
            int row = r0 + ty * 4 + i;
            f32x4 o;
#pragma unroll
            for (int j = 0; j < 4; j++)
                o[j] = silu_f(acc[i][j] + gb1[c0 + tx * 4 + j]);
            *(f32x4*)&hidden[(size_t)row * NG + c0 + tx * 4] = o;
        }
        return;
    }
    id -= 512;            // tconv ew1: tiles (64,16,8)
    int bx = id & 63, by = (id >> 6) & 15, e = id >> 10;
    tconv_body(ew1 + (size_t)e * NH * NF, Wt1 + (size_t)e * NH * NF,
               NH, NF, bx, by, smem);
}

// ---------------------------------------------------------------------------
// Router: softmax -> top2 -> threshold -> per-expert slot lists
// ---------------------------------------------------------------------------
__global__ __launch_bounds__(64) void k_router(
    const float* __restrict__ hidden, const float* __restrict__ w2,
    const float* __restrict__ b2, float* __restrict__ gw_out,
    int* __restrict__ count, int* __restrict__ slot_row,
    float* __restrict__ slot_w, float* __restrict__ row_total,
    int* __restrict__ row_fired)
{
    const int r = blockIdx.x;
    const int l = threadIdx.x;
    float pe[NE] = {};
    for (int k = l; k < NG; k += 64) {
        float h = hidden[(size_t)r * NG + k];
        const float* wr = w2 + (size_t)k * NE;
#pragma unroll
        for (int e = 0; e < NE; e++) pe[e] += h * wr[e];
    }
#pragma unroll
    for (int e = 0; e < NE; e++) {
#pragma unroll
        for (int m = 1; m < 64; m <<= 1) pe[e] += __shfl_xor(pe[e], m);
    }
    float logit[NE];
    float mx = -1e30f;
#pragma unroll
    for (int e = 0; e < NE; e++) { logit[e] = pe[e] + b2[e]; mx = fmaxf(mx, logit[e]); }
    float w[NE], s = 0.f;
#pragma unroll
    for (int e = 0; e < NE; e++) { w[e] = expf(logit[e] - mx); s += w[e]; }
    float inv = 1.f / s;
#pragma unroll
    for (int e = 0; e < NE; e++) w[e] *= inv;
    if (l < NE) gw_out[(size_t)r * NE + l] = w[l];

    int i1 = 0; float v1 = w[0];
#pragma unroll
    for (int e = 1; e < NE; e++) if (w[e] > v1) { v1 = w[e]; i1 = e; }
    int i2 = -1; float v2 = -1.f;
#pragma unroll
    for (int e = 0; e < NE; e++) if (e != i1 && w[e] > v2) { v2 = w[e]; i2 = e; }

    bool k1 = v1 > THRESH, k2 = v2 > THRESH;
    float total = (k1 ? v1 : 0.f) + (k2 ? v2 : 0.f);
    if (l == 0) {
        row_total[r] = total;
        row_fired[r] = (total > 0.f) ? 1 : 0;
        if (k1) { int p = atomicAdd(&count[i1], 1); slot_row[i1 * NB + p] = r; slot_w[i1 * NB + p] = v1; }
        if (k2) { int p = atomicAdd(&count[i2], 1); slot_row[i2 * NB + p] = r; slot_w[i2 * NB + p] = v2; }
    }
}

// ---------------------------------------------------------------------------
// Compacted bf16 x gather: Xc[slot] = bf16(x[slot_row]). Offsets from count.
// ---------------------------------------------------------------------------
__global__ __launch_bounds__(256) void k_xc(
    const float* __restrict__ x, const int* __restrict__ count,
    const int* __restrict__ slot_row, __bf16* __restrict__ Xc)
{
    const int s = blockIdx.x;
    int acc = 0, e = -1, off = 0;
#pragma unroll
    for (int i = 0; i < NE; i++) {
        if (s >= acc) { e = i; off = acc; }
        acc += count[i];
    }
    if (s >= acc) return;
    const int r = slot_row[e * NB + (s - off)];
    const float* src = x + (size_t)r * NH;
    __bf16* dst = Xc + (size_t)s * NH;
    const int t = threadIdx.x;
    f32x4 v = *(const f32x4*)(src + t * 4);
    bf16x4 o;
#pragma unroll
    for (int j = 0; j < 4; j++) o[j] = (__bf16)v[j];
    *(bf16x4*)(dst + t * 4) = o;
}

// ---------------------------------------------------------------------------
// Routed GEMM (R11 proven inner loop) + optional appended tconv blocks.
// GEMM blocks: blockIdx.x < X*NE. Extra blocks (bx >= X*NE) run tconv on
// (tcI -> tcO), tiles xT = tcC/64, yT = tcR/64, NE experts; they fill idle
// CU slots/BW while the latency-bound GEMM runs. No data hazard: tcO is
// consumed only by a LATER launch.
// OM: 0 = store bf16 compacted rows (+bias, silu if ACT), 1 = weighted
// f32 atomicAdd into d_out via slot lists.
// ---------------------------------------------------------------------------
template<int ACT, int OM>
__global__ __launch_bounds__(256) void k_gemm2(
    const __bf16* __restrict__ A, int lda,
    const __bf16* __restrict__ Wt, size_t wstride,
    const float* __restrict__ bias, int bstride,
    __bf16* __restrict__ outB, float* __restrict__ outF,
    int N, int Kd, int X,
    const int* __restrict__ count,
    const int* __restrict__ slot_row, const float* __restrict__ slot_w,
    const float* __restrict__ tcI, __bf16* __restrict__ tcO,
    int tcR, int tcC)
{
    __shared__ __align__(16) unsigned char lds[32768];
    const int bx = blockIdx.x;

    if (bx >= X * NE) {
        // ---- appended tconv blocks ----
        if (tcI) {
            int id = (bx - X * NE) * gridDim.y + blockIdx.y;
            int xT = tcC >> 6, yT = tcR >> 6;
            int per = xT * yT;
            int e = id / per, rem = id - e * per;
            int byy = rem / xT, bxx = rem - byy * xT;
            tconv_body(tcI + (size_t)e * tcR * tcC, tcO + (size_t)e * tcR * tcC,
                       tcR, tcC, bxx, byy, (float*)lds);
        }
        return;
    }

    unsigned char* sA = lds;            // [m][kslot] bf16, 16 KB
    unsigned char* sB = lds + 16384;    // [n][kslot] bf16, 16 KB

    const int e  = bx / X;
    const int n0 = (bx % X) * 128;
    const int cnt = count[e];
    const int row0 = blockIdx.y * 128;
    if (row0 >= cnt) return;
    int off = 0;
    for (int i = 0; i < NE; i++) off += (i < e) ? count[i] : 0;
    const __bf16* W = Wt + (size_t)e * wstride;
    const int tid = threadIdx.x;
    const int lane = tid & 63, wid = tid >> 6;
    const int wm = (wid >> 1) * 64, wn = (wid & 1) * 64;
    const int arow0 = off + row0;

    f32x4 acc[4][4];
#pragma unroll
    for (int mi = 0; mi < 4; mi++)
#pragma unroll
        for (int ni = 0; ni < 4; ni++)
            acc[mi][ni] = (f32x4){0.f, 0.f, 0.f, 0.f};

    const int sub = lane >> 3;            // 0..7 row within chunk
    const int kcx = (lane & 7) ^ sub;     // source k-chunk (inverse swizzle)

    for (int k0 = 0; k0 < Kd; k0 += 64) {
#pragma unroll
        for (int i = 0; i < 4; i++) {
            int c = wid * 4 + i;          // chunk 0..15 (8 rows each)
            int row = c * 8 + sub;
            gl_lds16(A + (size_t)(arow0 + row) * lda + k0 + kcx * 8,
                     sA + c * 1024 + lane * 16);
        }
#pragma unroll
        for (int i = 0; i < 4; i++) {
            int c = wid * 4 + i;
            int n = c * 8 + sub;
            gl_lds16(W + (size_t)(n0 + n) * Kd + k0 + kcx * 8,
                     sB + c * 1024 + lane * 16);
        }
        __syncthreads();
#pragma unroll
        for (int ks = 0; ks < 2; ks++) {
            bf16x8 af[4], bfr[4];
            const int kb = ks * 64 + ((lane >> 4) << 4);
#pragma unroll
            for (int mi = 0; mi < 4; mi++) {
                int row = wm + mi * 16 + (lane & 15);
                af[mi] = *(const bf16x8*)(sA + row * 128 + (kb ^ ((row & 7) << 4)));
            }
#pragma unroll
            for (int ni = 0; ni < 4; ni++) {
                int row = wn + ni * 16 + (lane & 15);
                bfr[ni] = *(const bf16x8*)(sB + row * 128 + (kb ^ ((row & 7) << 4)));
            }
#pragma unroll
            for (int mi = 0; mi < 4; mi++)
#pragma unroll
                for (int ni = 0; ni < 4; ni++)
                    acc[mi][ni] = __builtin_amdgcn_mfma_f32_16x16x32_bf16(
                        af[mi], bfr[ni], acc[mi][ni], 0, 0, 0);
        }
        __syncthreads();
    }

    const int q = lane >> 4, cl = lane & 15;
#pragma unroll
    for (int mi = 0; mi < 4; mi++) {
#pragma unroll
        for (int r = 0; r < 4; r++) {
            int srow = row0 + wm + mi * 16 + q * 4 + r;
            if (srow >= cnt) continue;
            if (OM == 0) {
#pragma unroll
                for (int ni = 0; ni < 4; ni++) {
                    int col = n0 + wn + ni * 16 + cl;
                    float vv = acc[mi][ni][r] + bias[(size_t)e * bstride + col];
                    if (ACT) vv = silu_f(vv);
                    outB[(size_t)(off + srow) * N + col] = (__bf16)vv;
                }
            } else {
                int grow = slot_row[e * NB + srow];
                float wsl = slot_w[e * NB + srow];
#pragma unroll
                for (int ni = 0; ni < 4; ni++) {
                    int col = n0 + wn + ni * 16 + cl;
                    atomicAdd(&outF[(size_t)grow * NH + col], wsl * acc[mi][ni][r]);
                }
            }
        }
    }
}

// ---------------------------------------------------------------------------
// Finalize IN-PLACE: out = fired ? a*(out/t) + (1-a)*x : x
// ---------------------------------------------------------------------------
__global__ __launch_bounds__(256) void k_final(
    const float* __restrict__ x,
    const float* __restrict__ row_total, const int* __restrict__ row_fired,
    const float* __restrict__ blend, float* __restrict__ out)
{
    int idx = blockIdx.x * 256 + threadIdx.x;
    int r = idx >> 8;
    int c = (idx & 255) << 2;
    float alpha = 1.f / (1.f + expf(-blend[0]));
    f32x4 cb = *(const f32x4*)(out + (size_t)r * NH + c);
    f32x4 xv = *(const f32x4*)(x + (size_t)r * NH + c);
    int fired = row_fired[r];
    float inv_t = fired ? (1.f / row_total[r]) : 0.f;
    f32x4 o;
#pragma unroll
    for (int j = 0; j < 4; j++)
        o[j] = fired ? (alpha * (cb[j] * inv_t) + (1.f - alpha) * xv[j]) : xv[j];
    *(f32x4*)&out[(size_t)r * NH + c] = o;
}

// ---------------------------------------------------------------------------
extern "C" void kernel_launch(void* const* d_in, const int* in_sizes, int n_in,
                              void* d_out, int out_size, void* d_ws, size_t ws_size,
                              hipStream_t stream)
{
    float* out_main = (float*)d_out;
    float* gw_out   = (float*)d_out + (size_t)NB * NH;

    static const long long EXP[11] = {
        (long long)NB * NH, (long long)NH * NG, NG, (long long)NG * NE, NE,
        (long long)NE * NH * NF, (long long)NE * NF,
        (long long)NE * NF * NH, (long long)NE * NH,
        (long long)NE * NH * NH, 1
    };
    bool ok = (n_in == 11);
    if (ok)
        for (int i = 0; i < 11; i++)
            if ((long long)in_sizes[i] != EXP[i]) { ok = false; break; }
    if (!ok) {
        k_sentinel<<<1, 1, 0, stream>>>((float*)d_out, 2000.f + n_in);
        return;
    }

    const float* x    = (const float*)d_in[0];
    const float* gw1  = (const float*)d_in[1];
    const float* gb1  = (const float*)d_in[2];
    const float* gw2  = (const float*)d_in[3];
    const float* gb2  = (const float*)d_in[4];
    const float* ew1  = (const float*)d_in[5];
    const float* eb1  = (const float*)d_in[6];
    const float* ew2  = (const float*)d_in[7];
    const float* eb2  = (const float*)d_in[8];
    const float* pw   = (const float*)d_in[9];
    const float* blnd = (const float*)d_in[10];

    // ---- workspace layout (identical to R11, proven fits) ----
    size_t need = 0;
    size_t off_meta   = need;   need += 512;
    size_t off_srow   = need;   need += (size_t)NE * NB * 4;
    size_t off_sw     = need;   need += (size_t)NE * NB * 4;
    size_t off_total  = need;   need += (size_t)NB * 4;
    size_t off_fired  = need;   need += (size_t)NB * 4;
    size_t off_hidden = need;   need += (size_t)NB * NG * 4;
    size_t a_xc  = need;
    size_t a_h1  = a_xc + ROWS * NH * 2;
    size_t a_h2  = a_h1 + ROWS * NF * 2;
    size_t a_w1  = a_h2 + ROWS * NH * 2;
    size_t a_w2  = a_w1 + (size_t)NE * NH * NF * 2;
    size_t a_wp  = a_w2 + (size_t)NE * NF * NH * 2;
    size_t need_A = a_wp + (size_t)NE * NH * NH * 2;

    char* ws = (char*)d_ws;
    int*   count     = (int*)(ws + off_meta);
    int*   slot_row  = (int*)(ws + off_srow);
    float* slot_w    = (float*)(ws + off_sw);
    float* row_total = (float*)(ws + off_total);
    int*   row_fired = (int*)(ws + off_fired);
    float* hidden    = (float*)(ws + off_hidden);

    if (ws_size < need_A) {
        k_sentinel<<<1, 1, 0, stream>>>((float*)d_out,
                                        1000.f + (float)(ws_size >> 20));
        return;
    }
    __bf16* Xc  = (__bf16*)(ws + a_xc);
    __bf16* H1  = (__bf16*)(ws + a_h1);
    __bf16* H2  = (__bf16*)(ws + a_h2);
    __bf16* Wt1 = (__bf16*)(ws + a_w1);
    __bf16* Wt2 = (__bf16*)(ws + a_w2);
    __bf16* Wtp = (__bf16*)(ws + a_wp);

    hipMemsetAsync(count, 0, 512, stream);
    hipMemsetAsync(out_main, 0, (size_t)NB * NH * 4, stream);

    // L1: gate + tconv(ew1)
    k_gate_ew1<<<dim3(512 + 8192), 256, 0, stream>>>(
        x, gw1, gb1, hidden, ew1, Wt1);

    k_router<<<dim3(NB), 64, 0, stream>>>(hidden, gw2, gb2, gw_out,
                                          count, slot_row, slot_w, row_total, row_fired);
    k_xc<<<dim3((int)MAXS), 256, 0, stream>>>(x, count, slot_row, Xc);

    // FFN1 (X=32 -> 256 GEMM bx) + tconv(ew2): 8192 tconv blocks = 256 bx x 32 y
    k_gemm2<1, 0><<<dim3(256 + 256, NB / 128), 256, 0, stream>>>(
        Xc, NH, Wt1, (size_t)NH * NF, eb1, NF,
        H1, nullptr, NF, NH, 32, count, slot_row, slot_w,
        ew2, Wt2, NF, NH);
    // FFN2 (X=8 -> 64 GEMM bx) + tconv(pw): 2048 tconv blocks = 64 bx x 32 y
    k_gemm2<0, 0><<<dim3(64 + 64, NB / 128), 256, 0, stream>>>(
        H1, NF, Wt2, (size_t)NF * NH, eb2, NH,
        H2, nullptr, NH, NF, 8, count, slot_row, slot_w,
        pw, Wtp, NH, NH);
    // PROJ (X=8), no appended work
    k_gemm2<0, 1><<<dim3(64, NB / 128), 256, 0, stream>>>(
        H2, NH, Wtp, (size_t)NH * NH, eb2 /*unused*/, 0,
        nullptr, out_main, NH, NH, 8, count, slot_row, slot_w,
        nullptr, nullptr, 0, 64);

    k_final<<<dim3(NB * NH / 1024), 256, 0, stream>>>(x, row_total,
                                                      row_fired, blnd, out_main);
}

// Round 19
// 485.483 us; speedup vs baseline: 1.1636x; 1.1636x over previous
//
#include <hip/hip_runtime.h>
#include <hip/hip_bf16.h>
#include <cmath>

constexpr int NB = 4096;   // batch
constexpr int NH = 1024;   // hidden
constexpr int NE = 8;      // experts
constexpr int NF = 4096;   // dff
constexpr int NG = 512;    // gate hidden (H/2)
constexpr float THRESH = 0.1f;
constexpr int PAD_ROWS = 128;
constexpr size_t MAXS = (size_t)2 * NB;        // <= 8192 routed slots
constexpr size_t ROWS = MAXS + PAD_ROWS;       // padded for tile overreach

// Established (rounds 0-18):
//   ALL inputs f32 C-order positional. d_out f32 [output(B,H) | gate_w(B,E)].
//   ws_size >= ~256 MiB. ~All top-2 pass threshold (S ~ 8175).
//   R11 gload_lds 128x128 GEMM best (121us FFN1); dbuf/supertile/8-phase lost.
//   R16 fused prework best (542 total); R17 vectorize / R18 co-schedule lost.
//   This round: gate blocks emit LOGITS directly (atomic partial reduce),
//   hidden buffer deleted, router shrunk to logits softmax/top2. Rest = R16.

typedef float  f32x4  __attribute__((ext_vector_type(4)));
typedef __bf16 bf16x8 __attribute__((ext_vector_type(8)));
typedef __bf16 bf16x4 __attribute__((ext_vector_type(4)));

typedef __attribute__((address_space(1))) void gvoid_t;
typedef __attribute__((address_space(3))) void svoid_t;

__device__ __forceinline__ void gl_lds16(const void* g, void* l)
{
    __builtin_amdgcn_global_load_lds((gvoid_t*)g, (svoid_t*)l, 16, 0, 0);
}

__device__ __forceinline__ float silu_f(float v) { return v / (1.f + expf(-v)); }

__global__ void k_sentinel(float* out, float code)
{
    if (threadIdx.x == 0 && blockIdx.x == 0) out[0] = code;
}

// ---------------------------------------------------------------------------
// tconv tile body: 64x64 f32 [R][C] tile -> bf16 [C][R], via LDS stride-65.
// (R16-proven version: scalar smem, bf16x4 writes)
// ---------------------------------------------------------------------------
__device__ __forceinline__ void tconv_body(
    const float* __restrict__ I, __bf16* __restrict__ O, int R, int C,
    int bx, int by, float* smem)
{
    const int r0 = by * 64, c0 = bx * 64;
    const int tid = threadIdx.x;
#pragma unroll
    for (int i = 0; i < 16; i++) {
        int idx = tid + i * 256;
        int r = idx >> 6, c = idx & 63;
        smem[r * 65 + c] = I[(size_t)(r0 + r) * C + c0 + c];
    }
    __syncthreads();
    const int cl = tid >> 4;      // 0..15
    const int rq = tid & 15;      // 0..15 -> rows rq*4..rq*4+3
#pragma unroll
    for (int i = 0; i < 4; i++) {
        int c = cl + i * 16;
        bf16x4 v;
#pragma unroll
        for (int j = 0; j < 4; j++)
            v[j] = (__bf16)smem[(rq * 4 + j) * 65 + c];
        *(bf16x4*)&O[(size_t)(c0 + c) * R + r0 + rq * 4] = v;
    }
}

// ---------------------------------------------------------------------------
// Fused pre-work: gate GEMM -> LOGITS (atomic partial) + 3 tconvs, 1 launch.
//   [0, 512)            gate: logits[r][e] += silu(x@gw1+gb1) @ gw2 (partial)
//   [512, 8704)         tconv ew1 [e][NH][NF] -> Wt1 [e][NF][NH] bf16
//   [8704, 16896)       tconv ew2 [e][NF][NH] -> Wt2 [e][NH][NF] bf16
//   [16896, 18944)      tconv pw  [e][NH][NH] -> Wtp [e][NH][NH] bf16
// hidden buffer eliminated: each gate block holds its silu tile in registers
// and reduces against gw2 (16KB, L2-resident); 16-lane shfl reduce then one
// atomicAdd per (row, expert) per c-block (8 adds/address total).
// ---------------------------------------------------------------------------
__global__ __launch_bounds__(256) void k_prework(
    const float* __restrict__ x, const float* __restrict__ gw1,
    const float* __restrict__ gb1, const float* __restrict__ gw2,
    float* __restrict__ logits,
    const float* __restrict__ ew1, __bf16* __restrict__ Wt1,
    const float* __restrict__ ew2, __bf16* __restrict__ Wt2,
    const float* __restrict__ pw,  __bf16* __restrict__ Wtp)
{
    __shared__ float smem[64 * 65];   // 16.6 KB
    int id = blockIdx.x;

    if (id < 512) {
        // ---- gate GEMM + partial logits ----
        float* As = smem;              // [16][68]
        float* Bs = smem + 16 * 68;    // [16][64]
        const int tid = threadIdx.x;
        const int r0 = (id >> 3) * 64, c0 = (id & 7) * 64;
        const int tx = tid & 15, ty = tid >> 4;
        float acc[4][4] = {};
        for (int k0 = 0; k0 < NH; k0 += 16) {
#pragma unroll
            for (int i = 0; i < 4; i++) {
                int e = tid + i * 256;
                int m = e >> 4, kk = e & 15;
                As[kk * 68 + m] = x[(size_t)(r0 + m) * NH + k0 + kk];
            }
#pragma unroll
            for (int i = 0; i < 4; i++) {
                int e = tid + i * 256;
                int kk = e >> 6, n = e & 63;
                Bs[kk * 64 + n] = gw1[(size_t)(k0 + kk) * NG + c0 + n];
            }
            __syncthreads();
#pragma unroll
            for (int kk = 0; kk < 16; kk++) {
                f32x4 a = *(const f32x4*)&As[kk * 68 + ty * 4];
                f32x4 b = *(const f32x4*)&Bs[kk * 64 + tx * 4];
#pragma unroll
                for (int i = 0; i < 4; i++)
#pragma unroll
                    for (int j = 0; j < 4; j++)
                        acc[i][j] = fmaf(a[i], b[j], acc[i][j]);
            }
            __syncthreads();
        }
        // silu + bias -> h tile in registers
#pragma unroll
        for (int i = 0; i < 4; i++)
#pragma unroll
            for (int j = 0; j < 4; j++)
                acc[i][j] = silu_f(acc[i][j] + gb1[c0 + tx * 4 + j]);
        // partial logits: pl[i][e] = sum_j h[i][j] * gw2[c0+tx*4+j][e]
        float pl[4][NE];
#pragma unroll
        for (int i = 0; i < 4; i++)
#pragma unroll
            for (int e = 0; e < NE; e++) pl[i][e] = 0.f;
#pragma unroll
        for (int j = 0; j < 4; j++) {
            const float* wr = gw2 + (size_t)(c0 + tx * 4 + j) * NE;
#pragma unroll
            for (int e = 0; e < NE; e++) {
                float w = wr[e];
#pragma unroll
                for (int i = 0; i < 4; i++)
                    pl[i][e] = fmaf(acc[i][j], w, pl[i][e]);
            }
        }
        // reduce over the 16-lane tx group
#pragma unroll
        for (int m = 1; m < 16; m <<= 1)
#pragma unroll
            for (int i = 0; i < 4; i++)
#pragma unroll
                for (int e = 0; e < NE; e++)
                    pl[i][e] += __shfl_xor(pl[i][e], m);
        if (tx == 0) {
#pragma unroll
            for (int i = 0; i < 4; i++)
#pragma unroll
                for (int e = 0; e < NE; e++)
                    atomicAdd(&logits[(size_t)(r0 + ty * 4 + i) * NE + e],
                              pl[i][e]);
        }
        return;
    }
    id -= 512;
    if (id < 8192) {      // tconv ew1: tiles (64,16,8)
        int bx = id & 63, by = (id >> 6) & 15, e = id >> 10;
        tconv_body(ew1 + (size_t)e * NH * NF, Wt1 + (size_t)e * NH * NF,
                   NH, NF, bx, by, smem);
        return;
    }
    id -= 8192;
    if (id < 8192) {      // tconv ew2: tiles (16,64,8)
        int bx = id & 15, by = (id >> 4) & 63, e = id >> 10;
        tconv_body(ew2 + (size_t)e * NF * NH, Wt2 + (size_t)e * NF * NH,
                   NF, NH, bx, by, smem);
        return;
    }
    id -= 8192;           // tconv pw: tiles (16,16,8)
    {
        int bx = id & 15, by = (id >> 4) & 15, e = id >> 8;
        tconv_body(pw + (size_t)e * NH * NH, Wtp + (size_t)e * NH * NH,
                   NH, NH, bx, by, smem);
    }
}

// ---------------------------------------------------------------------------
// Router-lite: one thread per row; softmax/top2/threshold from logits.
// ---------------------------------------------------------------------------
__global__ __launch_bounds__(256) void k_router_lite(
    const float* __restrict__ logits, const float* __restrict__ b2,
    float* __restrict__ gw_out,
    int* __restrict__ count, int* __restrict__ slot_row,
    float* __restrict__ slot_w, float* __restrict__ row_total,
    int* __restrict__ row_fired)
{
    const int r = blockIdx.x * 256 + threadIdx.x;
    if (r >= NB) return;
    float w[NE];
    float mx = -1e30f;
#pragma unroll
    for (int e = 0; e < NE; e++) {
        w[e] = logits[(size_t)r * NE + e] + b2[e];
        mx = fmaxf(mx, w[e]);
    }
    float s = 0.f;
#pragma unroll
    for (int e = 0; e < NE; e++) { w[e] = expf(w[e] - mx); s += w[e]; }
    float inv = 1.f / s;
#pragma unroll
    for (int e = 0; e < NE; e++) {
        w[e] *= inv;
        gw_out[(size_t)r * NE + e] = w[e];
    }
    int i1 = 0; float v1 = w[0];
#pragma unroll
    for (int e = 1; e < NE; e++) if (w[e] > v1) { v1 = w[e]; i1 = e; }
    int i2 = -1; float v2 = -1.f;
#pragma unroll
    for (int e = 0; e < NE; e++) if (e != i1 && w[e] > v2) { v2 = w[e]; i2 = e; }

    bool k1 = v1 > THRESH, k2 = v2 > THRESH;
    float total = (k1 ? v1 : 0.f) + (k2 ? v2 : 0.f);
    row_total[r] = total;
    row_fired[r] = (total > 0.f) ? 1 : 0;
    if (k1) { int p = atomicAdd(&count[i1], 1); slot_row[i1 * NB + p] = r; slot_w[i1 * NB + p] = v1; }
    if (k2) { int p = atomicAdd(&count[i2], 1); slot_row[i2 * NB + p] = r; slot_w[i2 * NB + p] = v2; }
}

__global__ void k_offsets(const int* __restrict__ count, int* __restrict__ offs)
{
    if (threadIdx.x == 0 && blockIdx.x == 0) {
        int s = 0;
        for (int e = 0; e < NE; e++) { offs[e] = s; s += count[e]; }
    }
}

// ---------------------------------------------------------------------------
// Compacted bf16 x gather: Xc[slot] = bf16(x[slot_row])
// ---------------------------------------------------------------------------
__global__ __launch_bounds__(256) void k_xc(
    const float* __restrict__ x, const int* __restrict__ count,
    const int* __restrict__ offs, const int* __restrict__ slot_row,
    __bf16* __restrict__ Xc)
{
    const int s = blockIdx.x;
    int e = 0;
#pragma unroll
    for (int i = 1; i < NE; i++) if (s >= offs[i]) e = i;
    if (s >= offs[NE - 1] + count[NE - 1]) return;
    const int r = slot_row[e * NB + (s - offs[e])];
    const float* src = x + (size_t)r * NH;
    __bf16* dst = Xc + (size_t)s * NH;
    const int t = threadIdx.x;
    f32x4 v = *(const f32x4*)(src + t * 4);
    bf16x4 o;
#pragma unroll
    for (int j = 0; j < 4; j++) o[j] = (__bf16)v[j];
    *(bf16x4*)(dst + t * 4) = o;
}

// ---------------------------------------------------------------------------
// Routed GEMM — R11/R16 proven version EXACT.
// ---------------------------------------------------------------------------
template<int ACT, int OM>
__global__ __launch_bounds__(256) void k_gemm2(
    const __bf16* __restrict__ A, int lda,
    const __bf16* __restrict__ Wt, size_t wstride,
    const float* __restrict__ bias, int bstride,
    __bf16* __restrict__ outB, float* __restrict__ outF,
    int N, int Kd, int X,
    const int* __restrict__ count, const int* __restrict__ offs,
    const int* __restrict__ slot_row, const float* __restrict__ slot_w)
{
    const int bx = blockIdx.x;
    const int e  = bx / X;
    const int n0 = (bx % X) * 128;
    const int cnt = count[e];
    const int row0 = blockIdx.y * 128;
    if (row0 >= cnt) return;
    const int off = offs[e];
    const __bf16* W = Wt + (size_t)e * wstride;
    const int tid = threadIdx.x;
    const int lane = tid & 63, wid = tid >> 6;
    const int wm = (wid >> 1) * 64, wn = (wid & 1) * 64;
    const int arow0 = off + row0;

    __shared__ __align__(16) unsigned char sA[16384];  // [m][kslot] bf16
    __shared__ __align__(16) unsigned char sB[16384];  // [n][kslot] bf16

    f32x4 acc[4][4];
#pragma unroll
    for (int mi = 0; mi < 4; mi++)
#pragma unroll
        for (int ni = 0; ni < 4; ni++)
            acc[mi][ni] = (f32x4){0.f, 0.f, 0.f, 0.f};

    const int sub = lane >> 3;            // 0..7 row within chunk
    const int kcx = (lane & 7) ^ sub;     // source k-chunk (inverse swizzle)

    for (int k0 = 0; k0 < Kd; k0 += 64) {
#pragma unroll
        for (int i = 0; i < 4; i++) {
            int c = wid * 4 + i;          // chunk 0..15 (8 rows each)
            int row = c * 8 + sub;
            gl_lds16(A + (size_t)(arow0 + row) * lda + k0 + kcx * 8,
                     sA + c * 1024 + lane * 16);
        }
#pragma unroll
        for (int i = 0; i < 4; i++) {
            int c = wid * 4 + i;
            int n = c * 8 + sub;
            gl_lds16(W + (size_t)(n0 + n) * Kd + k0 + kcx * 8,
                     sB + c * 1024 + lane * 16);
        }
        __syncthreads();
#pragma unroll
        for (int ks = 0; ks < 2; ks++) {
            bf16x8 af[4], bfr[4];
            const int kb = ks * 64 + ((lane >> 4) << 4);
#pragma unroll
            for (int mi = 0; mi < 4; mi++) {
                int row = wm + mi * 16 + (lane & 15);
                af[mi] = *(const bf16x8*)(sA + row * 128 + (kb ^ ((row & 7) << 4)));
            }
#pragma unroll
            for (int ni = 0; ni < 4; ni++) {
                int row = wn + ni * 16 + (lane & 15);
                bfr[ni] = *(const bf16x8*)(sB + row * 128 + (kb ^ ((row & 7) << 4)));
            }
#pragma unroll
            for (int mi = 0; mi < 4; mi++)
#pragma unroll
                for (int ni = 0; ni < 4; ni++)
                    acc[mi][ni] = __builtin_amdgcn_mfma_f32_16x16x32_bf16(
                        af[mi], bfr[ni], acc[mi][ni], 0, 0, 0);
        }
        __syncthreads();
    }

    const int q = lane >> 4, cl = lane & 15;
#pragma unroll
    for (int mi = 0; mi < 4; mi++) {
#pragma unroll
        for (int r = 0; r < 4; r++) {
            int srow = row0 + wm + mi * 16 + q * 4 + r;
            if (srow >= cnt) continue;
            if (OM == 0) {
#pragma unroll
                for (int ni = 0; ni < 4; ni++) {
                    int col = n0 + wn + ni * 16 + cl;
                    float vv = acc[mi][ni][r] + bias[(size_t)e * bstride + col];
                    if (ACT) vv = silu_f(vv);
                    outB[(size_t)(off + srow) * N + col] = (__bf16)vv;
                }
            } else {
                int grow = slot_row[e * NB + srow];
                float wsl = slot_w[e * NB + srow];
#pragma unroll
                for (int ni = 0; ni < 4; ni++) {
                    int col = n0 + wn + ni * 16 + cl;
                    atomicAdd(&outF[(size_t)grow * NH + col], wsl * acc[mi][ni][r]);
                }
            }
        }
    }
}

// ---------------------------------------------------------------------------
// Finalize IN-PLACE: out = fired ? a*(out/t) + (1-a)*x : x
// ---------------------------------------------------------------------------
__global__ __launch_bounds__(256) void k_final(
    const float* __restrict__ x,
    const float* __restrict__ row_total, const int* __restrict__ row_fired,
    const float* __restrict__ blend, float* __restrict__ out)
{
    int idx = blockIdx.x * 256 + threadIdx.x;
    int r = idx >> 8;
    int c = (idx & 255) << 2;
    float alpha = 1.f / (1.f + expf(-blend[0]));
    f32x4 cb = *(const f32x4*)(out + (size_t)r * NH + c);
    f32x4 xv = *(const f32x4*)(x + (size_t)r * NH + c);
    int fired = row_fired[r];
    float inv_t = fired ? (1.f / row_total[r]) : 0.f;
    f32x4 o;
#pragma unroll
    for (int j = 0; j < 4; j++)
        o[j] = fired ? (alpha * (cb[j] * inv_t) + (1.f - alpha) * xv[j]) : xv[j];
    *(f32x4*)&out[(size_t)r * NH + c] = o;
}

// ---------------------------------------------------------------------------
extern "C" void kernel_launch(void* const* d_in, const int* in_sizes, int n_in,
                              void* d_out, int out_size, void* d_ws, size_t ws_size,
                              hipStream_t stream)
{
    float* out_main = (float*)d_out;
    float* gw_out   = (float*)d_out + (size_t)NB * NH;

    static const long long EXP[11] = {
        (long long)NB * NH, (long long)NH * NG, NG, (long long)NG * NE, NE,
        (long long)NE * NH * NF, (long long)NE * NF,
        (long long)NE * NF * NH, (long long)NE * NH,
        (long long)NE * NH * NH, 1
    };
    bool ok = (n_in == 11);
    if (ok)
        for (int i = 0; i < 11; i++)
            if ((long long)in_sizes[i] != EXP[i]) { ok = false; break; }
    if (!ok) {
        k_sentinel<<<1, 1, 0, stream>>>((float*)d_out, 2000.f + n_in);
        return;
    }

    const float* x    = (const float*)d_in[0];
    const float* gw1  = (const float*)d_in[1];
    const float* gb1  = (const float*)d_in[2];
    const float* gw2  = (const float*)d_in[3];
    const float* gb2  = (const float*)d_in[4];
    const float* ew1  = (const float*)d_in[5];
    const float* eb1  = (const float*)d_in[6];
    const float* ew2  = (const float*)d_in[7];
    const float* eb2  = (const float*)d_in[8];
    const float* pw   = (const float*)d_in[9];
    const float* blnd = (const float*)d_in[10];

    // ---- workspace layout ----
    size_t need = 0;
    size_t off_meta   = need;   need += 512;
    size_t off_logits = need;   need += (size_t)NB * NE * 4;   // 128 KiB
    size_t off_srow   = need;   need += (size_t)NE * NB * 4;
    size_t off_sw     = need;   need += (size_t)NE * NB * 4;
    size_t off_total  = need;   need += (size_t)NB * 4;
    size_t off_fired  = need;   need += (size_t)NB * 4;
    size_t a_xc  = need;
    size_t a_h1  = a_xc + ROWS * NH * 2;
    size_t a_h2  = a_h1 + ROWS * NF * 2;
    size_t a_w1  = a_h2 + ROWS * NH * 2;
    size_t a_w2  = a_w1 + (size_t)NE * NH * NF * 2;
    size_t a_wp  = a_w2 + (size_t)NE * NF * NH * 2;
    size_t need_A = a_wp + (size_t)NE * NH * NH * 2;   // < R16's proven size

    char* ws = (char*)d_ws;
    int*   count     = (int*)(ws + off_meta);
    int*   offs      = count + 8;
    float* logits    = (float*)(ws + off_logits);
    int*   slot_row  = (int*)(ws + off_srow);
    float* slot_w    = (float*)(ws + off_sw);
    float* row_total = (float*)(ws + off_total);
    int*   row_fired = (int*)(ws + off_fired);

    if (ws_size < need_A) {
        k_sentinel<<<1, 1, 0, stream>>>((float*)d_out,
                                        1000.f + (float)(ws_size >> 20));
        return;
    }
    __bf16* Xc  = (__bf16*)(ws + a_xc);
    __bf16* H1  = (__bf16*)(ws + a_h1);
    __bf16* H2  = (__bf16*)(ws + a_h2);
    __bf16* Wt1 = (__bf16*)(ws + a_w1);
    __bf16* Wt2 = (__bf16*)(ws + a_w2);
    __bf16* Wtp = (__bf16*)(ws + a_wp);

    hipMemsetAsync(count, 0, 512 + (size_t)NB * NE * 4, stream); // meta+logits
    hipMemsetAsync(out_main, 0, (size_t)NB * NH * 4, stream);

    // Fused pre-work: gate->logits + all 3 weight transposes, one launch.
    k_prework<<<dim3(512 + 8192 + 8192 + 2048), 256, 0, stream>>>(
        x, gw1, gb1, gw2, logits, ew1, Wt1, ew2, Wt2, pw, Wtp);

    k_router_lite<<<dim3(NB / 256), 256, 0, stream>>>(
        logits, gb2, gw_out, count, slot_row, slot_w, row_total, row_fired);
    k_offsets<<<1, 1, 0, stream>>>(count, offs);
    k_xc<<<dim3((int)MAXS), 256, 0, stream>>>(x, count, offs, slot_row, Xc);

    // FFN1: H1 = silu(Xc @ ew1 + eb1)      X = NF/128 = 32
    k_gemm2<1, 0><<<dim3(32 * NE, NB / 128), 256, 0, stream>>>(
        Xc, NH, Wt1, (size_t)NH * NF, eb1, NF,
        H1, nullptr, NF, NH, 32, count, offs, slot_row, slot_w);
    // FFN2: H2 = H1 @ ew2 + eb2            X = NH/128 = 8
    k_gemm2<0, 0><<<dim3(8 * NE, NB / 128), 256, 0, stream>>>(
        H1, NF, Wt2, (size_t)NF * NH, eb2, NH,
        H2, nullptr, NH, NF, 8, count, offs, slot_row, slot_w);
    // PROJ: out += slot_w * (H2 @ pw)      X = 8
    k_gemm2<0, 1><<<dim3(8 * NE, NB / 128), 256, 0, stream>>>(
        H2, NH, Wtp, (size_t)NH * NH, eb2 /*unused*/, 0,
        nullptr, out_main, NH, NH, 8, count, offs, slot_row, slot_w);

    k_final<<<dim3(NB * NH / 1024), 256, 0, stream>>>(x, row_total,
                                                      row_fired, blnd, out_main);
}

// Round 20
// 472.073 us; speedup vs baseline: 1.1967x; 1.0284x over previous
//
#include <hip/hip_runtime.h>
#include <hip/hip_bf16.h>
#include <cmath>

constexpr int NB = 4096;   // batch
constexpr int NH = 1024;   // hidden
constexpr int NE = 8;      // experts
constexpr int NF = 4096;   // dff
constexpr int NG = 512;    // gate hidden (H/2)
constexpr float THRESH = 0.1f;
constexpr int PAD_ROWS = 128;
constexpr size_t MAXS = (size_t)2 * NB;        // <= 8192 routed slots
constexpr size_t ROWS = MAXS + PAD_ROWS;       // padded for tile overreach

// Established (rounds 0-19):
//   ALL inputs f32 C-order positional. d_out f32 [output(B,H) | gate_w(B,E)].
//   ws_size >= ~256 MiB. ~All top-2 pass threshold (S ~ 8175).
//   R11 gload_lds 128x128 GEMM best; dbuf/supertile/8-phase all falsified.
//   R19 (hidden-eliminated prework + router-lite) = 485 us best.
//   This round: tconv 128x64 tiles (2x DRAM page locality on transposed
//   writes) + offsets folded into router_lite (device-scope last-block).

typedef float  f32x4  __attribute__((ext_vector_type(4)));
typedef __bf16 bf16x8 __attribute__((ext_vector_type(8)));
typedef __bf16 bf16x4 __attribute__((ext_vector_type(4)));

typedef __attribute__((address_space(1))) void gvoid_t;
typedef __attribute__((address_space(3))) void svoid_t;

__device__ __forceinline__ void gl_lds16(const void* g, void* l)
{
    __builtin_amdgcn_global_load_lds((gvoid_t*)g, (svoid_t*)l, 16, 0, 0);
}

__device__ __forceinline__ float silu_f(float v) { return v / (1.f + expf(-v)); }

__global__ void k_sentinel(float* out, float code)
{
    if (threadIdx.x == 0 && blockIdx.x == 0) out[0] = code;
}

// ---------------------------------------------------------------------------
// tconv tile body: 128x64 f32 [R][C] tile -> bf16 [C][R] via LDS stride-65.
// Read: 8 iters f32x4 (256B row segments, 2-way banks).
// Write: 4 iters bf16x8 (128B col segments, adjacent halves back-to-back ->
// 256B/page per block; 2-way banks).
// ---------------------------------------------------------------------------
__device__ __forceinline__ void tconv_body(
    const float* __restrict__ I, __bf16* __restrict__ O, int R, int C,
    int bx, int by, float* smem)
{
    const int r0 = by * 128, c0 = bx * 64;
    const int tid = threadIdx.x;
    const int rr = tid >> 4;          // 0..15
    const int c4 = tid & 15;          // cols c4*4..c4*4+3
#pragma unroll
    for (int i = 0; i < 8; i++) {
        int r = i * 16 + rr;
        f32x4 v = *(const f32x4*)&I[(size_t)(r0 + r) * C + c0 + c4 * 4];
#pragma unroll
        for (int j = 0; j < 4; j++) smem[r * 65 + c4 * 4 + j] = v[j];
    }
    __syncthreads();
    const int cw = tid >> 3;          // 0..31
    const int rp = tid & 7;           // rows rp*8..rp*8+7
#pragma unroll
    for (int ri = 0; ri < 2; ri++) {
#pragma unroll
        for (int ci = 0; ci < 2; ci++) {
            int c = cw + ci * 32;
            int rb = ri * 64 + rp * 8;
            bf16x8 v;
#pragma unroll
            for (int j = 0; j < 8; j++)
                v[j] = (__bf16)smem[(rb + j) * 65 + c];
            *(bf16x8*)&O[(size_t)(c0 + c) * R + r0 + rb] = v;
        }
    }
}

// ---------------------------------------------------------------------------
// Fused pre-work: gate GEMM -> LOGITS (atomic partial) + 3 tconvs, 1 launch.
//   [0, 512)            gate: logits[r][e] += silu(x@gw1+gb1) @ gw2 (partial)
//   [512, 4608)         tconv ew1 [e][1024][4096] -> Wt1   (512 tiles/e)
//   [4608, 8704)        tconv ew2 [e][4096][1024] -> Wt2   (512 tiles/e)
//   [8704, 9728)        tconv pw  [e][1024][1024] -> Wtp   (128 tiles/e)
// ---------------------------------------------------------------------------
__global__ __launch_bounds__(256) void k_prework(
    const float* __restrict__ x, const float* __restrict__ gw1,
    const float* __restrict__ gb1, const float* __restrict__ gw2,
    float* __restrict__ logits,
    const float* __restrict__ ew1, __bf16* __restrict__ Wt1,
    const float* __restrict__ ew2, __bf16* __restrict__ Wt2,
    const float* __restrict__ pw,  __bf16* __restrict__ Wtp)
{
    __shared__ float smem[128 * 65];   // 33.3 KB
    int id = blockIdx.x;

    if (id < 512) {
        // ---- gate GEMM + partial logits (R19-proven body) ----
        float* As = smem;              // [16][68]
        float* Bs = smem + 16 * 68;    // [16][64]
        const int tid = threadIdx.x;
        const int r0 = (id >> 3) * 64, c0 = (id & 7) * 64;
        const int tx = tid & 15, ty = tid >> 4;
        float acc[4][4] = {};
        for (int k0 = 0; k0 < NH; k0 += 16) {
#pragma unroll
            for (int i = 0; i < 4; i++) {
                int e = tid + i * 256;
                int m = e >> 4, kk = e & 15;
                As[kk * 68 + m] = x[(size_t)(r0 + m) * NH + k0 + kk];
            }
#pragma unroll
            for (int i = 0; i < 4; i++) {
                int e = tid + i * 256;
                int kk = e >> 6, n = e & 63;
                Bs[kk * 64 + n] = gw1[(size_t)(k0 + kk) * NG + c0 + n];
            }
            __syncthreads();
#pragma unroll
            for (int kk = 0; kk < 16; kk++) {
                f32x4 a = *(const f32x4*)&As[kk * 68 + ty * 4];
                f32x4 b = *(const f32x4*)&Bs[kk * 64 + tx * 4];
#pragma unroll
                for (int i = 0; i < 4; i++)
#pragma unroll
                    for (int j = 0; j < 4; j++)
                        acc[i][j] = fmaf(a[i], b[j], acc[i][j]);
            }
            __syncthreads();
        }
#pragma unroll
        for (int i = 0; i < 4; i++)
#pragma unroll
            for (int j = 0; j < 4; j++)
                acc[i][j] = silu_f(acc[i][j] + gb1[c0 + tx * 4 + j]);
        float pl[4][NE];
#pragma unroll
        for (int i = 0; i < 4; i++)
#pragma unroll
            for (int e = 0; e < NE; e++) pl[i][e] = 0.f;
#pragma unroll
        for (int j = 0; j < 4; j++) {
            const float* wr = gw2 + (size_t)(c0 + tx * 4 + j) * NE;
#pragma unroll
            for (int e = 0; e < NE; e++) {
                float w = wr[e];
#pragma unroll
                for (int i = 0; i < 4; i++)
                    pl[i][e] = fmaf(acc[i][j], w, pl[i][e]);
            }
        }
#pragma unroll
        for (int m = 1; m < 16; m <<= 1)
#pragma unroll
            for (int i = 0; i < 4; i++)
#pragma unroll
                for (int e = 0; e < NE; e++)
                    pl[i][e] += __shfl_xor(pl[i][e], m);
        if (tx == 0) {
#pragma unroll
            for (int i = 0; i < 4; i++)
#pragma unroll
                for (int e = 0; e < NE; e++)
                    atomicAdd(&logits[(size_t)(r0 + ty * 4 + i) * NE + e],
                              pl[i][e]);
        }
        return;
    }
    id -= 512;
    if (id < 4096) {      // ew1: c-tiles 64, r-tiles 8
        int bx = id & 63, by = (id >> 6) & 7, e = id >> 9;
        tconv_body(ew1 + (size_t)e * NH * NF, Wt1 + (size_t)e * NH * NF,
                   NH, NF, bx, by, smem);
        return;
    }
    id -= 4096;
    if (id < 4096) {      // ew2: c-tiles 16, r-tiles 32
        int bx = id & 15, by = (id >> 4) & 31, e = id >> 9;
        tconv_body(ew2 + (size_t)e * NF * NH, Wt2 + (size_t)e * NF * NH,
                   NF, NH, bx, by, smem);
        return;
    }
    id -= 4096;           // pw: c-tiles 16, r-tiles 8
    {
        int bx = id & 15, by = (id >> 4) & 7, e = id >> 7;
        tconv_body(pw + (size_t)e * NH * NH, Wtp + (size_t)e * NH * NH,
                   NH, NH, bx, by, smem);
    }
}

// ---------------------------------------------------------------------------
// Router-lite: one thread/row softmax/top2/threshold + last-block offsets.
// ---------------------------------------------------------------------------
__global__ __launch_bounds__(256) void k_router_lite(
    const float* __restrict__ logits, const float* __restrict__ b2,
    float* __restrict__ gw_out,
    int* __restrict__ count, int* __restrict__ done, int* __restrict__ offs,
    int* __restrict__ slot_row,
    float* __restrict__ slot_w, float* __restrict__ row_total,
    int* __restrict__ row_fired)
{
    const int r = blockIdx.x * 256 + threadIdx.x;
    float w[NE];
    float mx = -1e30f;
#pragma unroll
    for (int e = 0; e < NE; e++) {
        w[e] = logits[(size_t)r * NE + e] + b2[e];
        mx = fmaxf(mx, w[e]);
    }
    float s = 0.f;
#pragma unroll
    for (int e = 0; e < NE; e++) { w[e] = expf(w[e] - mx); s += w[e]; }
    float inv = 1.f / s;
#pragma unroll
    for (int e = 0; e < NE; e++) {
        w[e] *= inv;
        gw_out[(size_t)r * NE + e] = w[e];
    }
    int i1 = 0; float v1 = w[0];
#pragma unroll
    for (int e = 1; e < NE; e++) if (w[e] > v1) { v1 = w[e]; i1 = e; }
    int i2 = -1; float v2 = -1.f;
#pragma unroll
    for (int e = 0; e < NE; e++) if (e != i1 && w[e] > v2) { v2 = w[e]; i2 = e; }

    bool k1 = v1 > THRESH, k2 = v2 > THRESH;
    float total = (k1 ? v1 : 0.f) + (k2 ? v2 : 0.f);
    row_total[r] = total;
    row_fired[r] = (total > 0.f) ? 1 : 0;
    if (k1) { int p = atomicAdd(&count[i1], 1); slot_row[i1 * NB + p] = r; slot_w[i1 * NB + p] = v1; }
    if (k2) { int p = atomicAdd(&count[i2], 1); slot_row[i2 * NB + p] = r; slot_w[i2 * NB + p] = v2; }

    // last finished block computes the 8-entry prefix (device-scope atomics)
    __threadfence();
    __syncthreads();
    if (threadIdx.x == 0) {
        int d = atomicAdd(done, 1);
        if (d == (int)gridDim.x - 1) {
            int acc = 0;
            for (int e = 0; e < NE; e++) { offs[e] = acc; acc += count[e]; }
            __threadfence();
        }
    }
}

// ---------------------------------------------------------------------------
// Compacted bf16 x gather: Xc[slot] = bf16(x[slot_row])
// ---------------------------------------------------------------------------
__global__ __launch_bounds__(256) void k_xc(
    const float* __restrict__ x, const int* __restrict__ count,
    const int* __restrict__ offs, const int* __restrict__ slot_row,
    __bf16* __restrict__ Xc)
{
    const int s = blockIdx.x;
    int e = 0;
#pragma unroll
    for (int i = 1; i < NE; i++) if (s >= offs[i]) e = i;
    if (s >= offs[NE - 1] + count[NE - 1]) return;
    const int r = slot_row[e * NB + (s - offs[e])];
    const float* src = x + (size_t)r * NH;
    __bf16* dst = Xc + (size_t)s * NH;
    const int t = threadIdx.x;
    f32x4 v = *(const f32x4*)(src + t * 4);
    bf16x4 o;
#pragma unroll
    for (int j = 0; j < 4; j++) o[j] = (__bf16)v[j];
    *(bf16x4*)(dst + t * 4) = o;
}

// ---------------------------------------------------------------------------
// Routed GEMM — R11/R16 proven version EXACT.
// ---------------------------------------------------------------------------
template<int ACT, int OM>
__global__ __launch_bounds__(256) void k_gemm2(
    const __bf16* __restrict__ A, int lda,
    const __bf16* __restrict__ Wt, size_t wstride,
    const float* __restrict__ bias, int bstride,
    __bf16* __restrict__ outB, float* __restrict__ outF,
    int N, int Kd, int X,
    const int* __restrict__ count, const int* __restrict__ offs,
    const int* __restrict__ slot_row, const float* __restrict__ slot_w)
{
    const int bx = blockIdx.x;
    const int e  = bx / X;
    const int n0 = (bx % X) * 128;
    const int cnt = count[e];
    const int row0 = blockIdx.y * 128;
    if (row0 >= cnt) return;
    const int off = offs[e];
    const __bf16* W = Wt + (size_t)e * wstride;
    const int tid = threadIdx.x;
    const int lane = tid & 63, wid = tid >> 6;
    const int wm = (wid >> 1) * 64, wn = (wid & 1) * 64;
    const int arow0 = off + row0;

    __shared__ __align__(16) unsigned char sA[16384];  // [m][kslot] bf16
    __shared__ __align__(16) unsigned char sB[16384];  // [n][kslot] bf16

    f32x4 acc[4][4];
#pragma unroll
    for (int mi = 0; mi < 4; mi++)
#pragma unroll
        for (int ni = 0; ni < 4; ni++)
            acc[mi][ni] = (f32x4){0.f, 0.f, 0.f, 0.f};

    const int sub = lane >> 3;            // 0..7 row within chunk
    const int kcx = (lane & 7) ^ sub;     // source k-chunk (inverse swizzle)

    for (int k0 = 0; k0 < Kd; k0 += 64) {
#pragma unroll
        for (int i = 0; i < 4; i++) {
            int c = wid * 4 + i;          // chunk 0..15 (8 rows each)
            int row = c * 8 + sub;
            gl_lds16(A + (size_t)(arow0 + row) * lda + k0 + kcx * 8,
                     sA + c * 1024 + lane * 16);
        }
#pragma unroll
        for (int i = 0; i < 4; i++) {
            int c = wid * 4 + i;
            int n = c * 8 + sub;
            gl_lds16(W + (size_t)(n0 + n) * Kd + k0 + kcx * 8,
                     sB + c * 1024 + lane * 16);
        }
        __syncthreads();
#pragma unroll
        for (int ks = 0; ks < 2; ks++) {
            bf16x8 af[4], bfr[4];
            const int kb = ks * 64 + ((lane >> 4) << 4);
#pragma unroll
            for (int mi = 0; mi < 4; mi++) {
                int row = wm + mi * 16 + (lane & 15);
                af[mi] = *(const bf16x8*)(sA + row * 128 + (kb ^ ((row & 7) << 4)));
            }
#pragma unroll
            for (int ni = 0; ni < 4; ni++) {
                int row = wn + ni * 16 + (lane & 15);
                bfr[ni] = *(const bf16x8*)(sB + row * 128 + (kb ^ ((row & 7) << 4)));
            }
#pragma unroll
            for (int mi = 0; mi < 4; mi++)
#pragma unroll
                for (int ni = 0; ni < 4; ni++)
                    acc[mi][ni] = __builtin_amdgcn_mfma_f32_16x16x32_bf16(
                        af[mi], bfr[ni], acc[mi][ni], 0, 0, 0);
        }
        __syncthreads();
    }

    const int q = lane >> 4, cl = lane & 15;
#pragma unroll
    for (int mi = 0; mi < 4; mi++) {
#pragma unroll
        for (int r = 0; r < 4; r++) {
            int srow = row0 + wm + mi * 16 + q * 4 + r;
            if (srow >= cnt) continue;
            if (OM == 0) {
#pragma unroll
                for (int ni = 0; ni < 4; ni++) {
                    int col = n0 + wn + ni * 16 + cl;
                    float vv = acc[mi][ni][r] + bias[(size_t)e * bstride + col];
                    if (ACT) vv = silu_f(vv);
                    outB[(size_t)(off + srow) * N + col] = (__bf16)vv;
                }
            } else {
                int grow = slot_row[e * NB + srow];
                float wsl = slot_w[e * NB + srow];
#pragma unroll
                for (int ni = 0; ni < 4; ni++) {
                    int col = n0 + wn + ni * 16 + cl;
                    atomicAdd(&outF[(size_t)grow * NH + col], wsl * acc[mi][ni][r]);
                }
            }
        }
    }
}

// ---------------------------------------------------------------------------
// Finalize IN-PLACE: out = fired ? a*(out/t) + (1-a)*x : x
// ---------------------------------------------------------------------------
__global__ __launch_bounds__(256) void k_final(
    const float* __restrict__ x,
    const float* __restrict__ row_total, const int* __restrict__ row_fired,
    const float* __restrict__ blend, float* __restrict__ out)
{
    int idx = blockIdx.x * 256 + threadIdx.x;
    int r = idx >> 8;
    int c = (idx & 255) << 2;
    float alpha = 1.f / (1.f + expf(-blend[0]));
    f32x4 cb = *(const f32x4*)(out + (size_t)r * NH + c);
    f32x4 xv = *(const f32x4*)(x + (size_t)r * NH + c);
    int fired = row_fired[r];
    float inv_t = fired ? (1.f / row_total[r]) : 0.f;
    f32x4 o;
#pragma unroll
    for (int j = 0; j < 4; j++)
        o[j] = fired ? (alpha * (cb[j] * inv_t) + (1.f - alpha) * xv[j]) : xv[j];
    *(f32x4*)&out[(size_t)r * NH + c] = o;
}

// ---------------------------------------------------------------------------
extern "C" void kernel_launch(void* const* d_in, const int* in_sizes, int n_in,
                              void* d_out, int out_size, void* d_ws, size_t ws_size,
                              hipStream_t stream)
{
    float* out_main = (float*)d_out;
    float* gw_out   = (float*)d_out + (size_t)NB * NH;

    static const long long EXP[11] = {
        (long long)NB * NH, (long long)NH * NG, NG, (long long)NG * NE, NE,
        (long long)NE * NH * NF, (long long)NE * NF,
        (long long)NE * NF * NH, (long long)NE * NH,
        (long long)NE * NH * NH, 1
    };
    bool ok = (n_in == 11);
    if (ok)
        for (int i = 0; i < 11; i++)
            if ((long long)in_sizes[i] != EXP[i]) { ok = false; break; }
    if (!ok) {
        k_sentinel<<<1, 1, 0, stream>>>((float*)d_out, 2000.f + n_in);
        return;
    }

    const float* x    = (const float*)d_in[0];
    const float* gw1  = (const float*)d_in[1];
    const float* gb1  = (const float*)d_in[2];
    const float* gw2  = (const float*)d_in[3];
    const float* gb2  = (const float*)d_in[4];
    const float* ew1  = (const float*)d_in[5];
    const float* eb1  = (const float*)d_in[6];
    const float* ew2  = (const float*)d_in[7];
    const float* eb2  = (const float*)d_in[8];
    const float* pw   = (const float*)d_in[9];
    const float* blnd = (const float*)d_in[10];

    // ---- workspace layout ----
    size_t need = 0;
    size_t off_meta   = need;   need += 512;                   // count/done/offs
    size_t off_logits = need;   need += (size_t)NB * NE * 4;   // 128 KiB
    size_t off_srow   = need;   need += (size_t)NE * NB * 4;
    size_t off_sw     = need;   need += (size_t)NE * NB * 4;
    size_t off_total  = need;   need += (size_t)NB * 4;
    size_t off_fired  = need;   need += (size_t)NB * 4;
    size_t a_xc  = need;
    size_t a_h1  = a_xc + ROWS * NH * 2;
    size_t a_h2  = a_h1 + ROWS * NF * 2;
    size_t a_w1  = a_h2 + ROWS * NH * 2;
    size_t a_w2  = a_w1 + (size_t)NE * NH * NF * 2;
    size_t a_wp  = a_w2 + (size_t)NE * NF * NH * 2;
    size_t need_A = a_wp + (size_t)NE * NH * NH * 2;

    char* ws = (char*)d_ws;
    int*   count     = (int*)(ws + off_meta);
    int*   done      = count + 8;
    int*   offs      = count + 16;
    float* logits    = (float*)(ws + off_logits);
    int*   slot_row  = (int*)(ws + off_srow);
    float* slot_w    = (float*)(ws + off_sw);
    float* row_total = (float*)(ws + off_total);
    int*   row_fired = (int*)(ws + off_fired);

    if (ws_size < need_A) {
        k_sentinel<<<1, 1, 0, stream>>>((float*)d_out,
                                        1000.f + (float)(ws_size >> 20));
        return;
    }
    __bf16* Xc  = (__bf16*)(ws + a_xc);
    __bf16* H1  = (__bf16*)(ws + a_h1);
    __bf16* H2  = (__bf16*)(ws + a_h2);
    __bf16* Wt1 = (__bf16*)(ws + a_w1);
    __bf16* Wt2 = (__bf16*)(ws + a_w2);
    __bf16* Wtp = (__bf16*)(ws + a_wp);

    hipMemsetAsync(count, 0, 512 + (size_t)NB * NE * 4, stream); // meta+logits
    hipMemsetAsync(out_main, 0, (size_t)NB * NH * 4, stream);

    // Fused pre-work: gate->logits + all 3 weight transposes (128x64 tiles).
    k_prework<<<dim3(512 + 4096 + 4096 + 1024), 256, 0, stream>>>(
        x, gw1, gb1, gw2, logits, ew1, Wt1, ew2, Wt2, pw, Wtp);

    k_router_lite<<<dim3(NB / 256), 256, 0, stream>>>(
        logits, gb2, gw_out, count, done, offs,
        slot_row, slot_w, row_total, row_fired);
    k_xc<<<dim3((int)MAXS), 256, 0, stream>>>(x, count, offs, slot_row, Xc);

    // FFN1: H1 = silu(Xc @ ew1 + eb1)      X = NF/128 = 32
    k_gemm2<1, 0><<<dim3(32 * NE, NB / 128), 256, 0, stream>>>(
        Xc, NH, Wt1, (size_t)NH * NF, eb1, NF,
        H1, nullptr, NF, NH, 32, count, offs, slot_row, slot_w);
    // FFN2: H2 = H1 @ ew2 + eb2            X = NH/128 = 8
    k_gemm2<0, 0><<<dim3(8 * NE, NB / 128), 256, 0, stream>>>(
        H1, NF, Wt2, (size_t)NF * NH, eb2, NH,
        H2, nullptr, NH, NF, 8, count, offs, slot_row, slot_w);
    // PROJ: out += slot_w * (H2 @ pw)      X = 8
    k_gemm2<0, 1><<<dim3(8 * NE, NB / 128), 256, 0, stream>>>(
        H2, NH, Wtp, (size_t)NH * NH, eb2 /*unused*/, 0,
        nullptr, out_main, NH, NH, 8, count, offs, slot_row, slot_w);

    k_final<<<dim3(NB * NH / 1024), 256, 0, stream>>>(x, row_total,
                                                      row_fired, blnd, out_main);
}